// Round 1
// baseline (82.022 us; speedup 1.0000x reference)
//
#include <hip/hip_runtime.h>
#include <hip/hip_bf16.h>
#include <stdint.h>

// Flash-attention forward: B=16, Lq=Lk=2048, D=64, fp32 in/out, bf16 MFMA.
// Reference mask fill is -1e6 -> exp underflows to exactly 0 in fp32, so
// restricting to the first valid_lens[b] keys is exact.

#define BATCH 16
#define SEQ   2048
#define DIM   64
#define KBLK  64
#define QBLK  64      // per block: 2 waves x 32 q-rows
#define NTHR  128

typedef __bf16 bf16x8 __attribute__((ext_vector_type(8)));
typedef float  f32x16 __attribute__((ext_vector_type(16)));
typedef unsigned int u32x2 __attribute__((ext_vector_type(2)));

static constexpr float QSCALE = 0.125f * 1.44269504088896340736f; // 1/sqrt(D)*log2(e)

__device__ __forceinline__ uint32_t pk2bf(float a, float b) {
    union { __hip_bfloat162 h; uint32_t u; } c;
    c.h = __float22bfloat162_rn(make_float2(a, b));
    return c.u;
}
__device__ __forceinline__ unsigned short bf1(float a) {
    union { __hip_bfloat16 h; unsigned short u; } c;
    c.h = __float2bfloat16(a);
    return c.u;
}
// XOR swizzle: row-major [row][64 bf16] tile, 128B rows; spreads the
// 32-lane column read across 8 16B slots (guide G4).
__device__ __forceinline__ uint32_t swz(uint32_t row, uint32_t colByte) {
    return row * 128u + (colByte ^ ((row & 7u) << 4));
}
__device__ __forceinline__ bf16x8 lds8(const char* p) {
    union { uint4 q; bf16x8 v; } c;
    c.q = *(const uint4*)p;
    return c.v;
}
__device__ __forceinline__ bf16x8 mk8(uint32_t w0, uint32_t w1, uint32_t w2, uint32_t w3) {
    union { uint32_t u[4]; bf16x8 v; } c;
    c.u[0] = w0; c.u[1] = w1; c.u[2] = w2; c.u[3] = w3;
    return c.v;
}
__device__ __forceinline__ u32x2 plswap(uint32_t a, uint32_t b) {
    return __builtin_amdgcn_permlane32_swap(a, b, false, false);
}
__device__ __forceinline__ float vmax16(const f32x16& v) {
    float a = fmaxf(fmaxf(v[0], v[1]), fmaxf(v[2], v[3]));
    float b = fmaxf(fmaxf(v[4], v[5]), fmaxf(v[6], v[7]));
    float c = fmaxf(fmaxf(v[8], v[9]), fmaxf(v[10], v[11]));
    float d = fmaxf(fmaxf(v[12], v[13]), fmaxf(v[14], v[15]));
    return fmaxf(fmaxf(a, b), fmaxf(c, d));
}
__device__ __forceinline__ float vsum16(const f32x16& v) {
    float a = (v[0] + v[1]) + (v[2] + v[3]);
    float b = (v[4] + v[5]) + (v[6] + v[7]);
    float c = (v[8] + v[9]) + (v[10] + v[11]);
    float d = (v[12] + v[13]) + (v[14] + v[15]);
    return (a + b) + (c + d);
}

__global__ __launch_bounds__(NTHR) void attn_fwd(
        const float* __restrict__ Q, const float* __restrict__ K,
        const float* __restrict__ V, const int* __restrict__ VL,
        float* __restrict__ O)
{
    __shared__ unsigned short kls[KBLK * DIM]; // [k][d] bf16, swizzled
    __shared__ unsigned short vls[DIM * KBLK]; // [d][k] bf16 (transposed), swizzled

    const int tid  = threadIdx.x;
    const int bid  = blockIdx.x;
    const int b    = bid & (BATCH - 1);   // consecutive bids -> different batch -> batch b on XCD b%8
    const int qt   = bid >> 4;            // 0..31
    const int qb   = qt * QBLK;
    const int wv   = tid >> 6;            // wave 0..1
    const int lane = tid & 63;
    const int h    = lane >> 5;           // lane half
    const int ln   = lane & 31;

    const int valid  = VL[b];
    const int ntiles = (valid + KBLK - 1) / KBLK;

    const size_t bOff = (size_t)b * SEQ * DIM;
    const int qrow = qb + wv * 32 + ln;

    // ---- Q fragments (B-operand layout for S^T = K * Q^T), scaled by 1/8*log2e ----
    bf16x8 qf[4];
    {
        const float* qp = Q + bOff + (size_t)qrow * DIM;
        #pragma unroll
        for (int s = 0; s < 4; ++s) {
            int c0 = s * 16 + h * 8;
            float4 x = *(const float4*)(qp + c0);
            float4 y = *(const float4*)(qp + c0 + 4);
            qf[s] = mk8(pk2bf(x.x * QSCALE, x.y * QSCALE),
                        pk2bf(x.z * QSCALE, x.w * QSCALE),
                        pk2bf(y.x * QSCALE, y.y * QSCALE),
                        pk2bf(y.z * QSCALE, y.w * QSCALE));
        }
    }

    f32x16 o0, o1;           // O^T accumulators: tile0 d=0..31 rows, tile1 d=32..63; col q=ln
    #pragma unroll
    for (int r = 0; r < 16; ++r) { o0[r] = 0.0f; o1[r] = 0.0f; }
    float m_run = -1e30f, l_run = 0.0f;

    const float* Kb = K + bOff;
    const float* Vb = V + bOff;
    const char* klsb = (const char*)kls;
    const char* vlsb = (const char*)vls;

    for (int kt = 0; kt < ntiles; ++kt) {
        const int kb = kt * KBLK;

        // ---- stage K (row-major) and V (transposed) tiles as bf16 ----
        #pragma unroll
        for (int p = 0; p < 8; ++p) {
            int idx = p * NTHR + tid;            // 0..1023
            int r = idx >> 4;                    // 0..63 (kv row)
            int c = (idx & 15) * 4;              // 0..60 (d col)
            float4 kx = *(const float4*)(Kb + (size_t)(kb + r) * DIM + c);
            *(uint2*)((char*)kls + swz(r, c * 2)) = make_uint2(pk2bf(kx.x, kx.y), pk2bf(kx.z, kx.w));
            float4 vx = *(const float4*)(Vb + (size_t)(kb + r) * DIM + c);
            *(unsigned short*)((char*)vls + swz(c + 0, r * 2)) = bf1(vx.x);
            *(unsigned short*)((char*)vls + swz(c + 1, r * 2)) = bf1(vx.y);
            *(unsigned short*)((char*)vls + swz(c + 2, r * 2)) = bf1(vx.z);
            *(unsigned short*)((char*)vls + swz(c + 3, r * 2)) = bf1(vx.w);
        }
        __syncthreads();

        // ---- S^T = K * Q^T  (two 32x32 tiles over k; lane col = q) ----
        f32x16 st0, st1;
        #pragma unroll
        for (int r = 0; r < 16; ++r) { st0[r] = 0.0f; st1[r] = 0.0f; }
        #pragma unroll
        for (int s = 0; s < 4; ++s) {
            int cb = (s * 16 + h * 8) * 2;
            bf16x8 a0 = lds8(klsb + swz(ln,      cb));
            bf16x8 a1 = lds8(klsb + swz(ln + 32, cb));
            st0 = __builtin_amdgcn_mfma_f32_32x32x16_bf16(a0, qf[s], st0, 0, 0, 0);
            st1 = __builtin_amdgcn_mfma_f32_32x32x16_bf16(a1, qf[s], st1, 0, 0, 0);
        }

        // ---- mask partial tail tile (exactly reproduces -1e6 fill: weight 0) ----
        if (kb + KBLK > valid) {
            #pragma unroll
            for (int r = 0; r < 16; ++r) {
                int krel = (r & 3) + 8 * (r >> 2) + 4 * h;
                if (kb + krel      >= valid) st0[r] = -1e30f;
                if (kb + 32 + krel >= valid) st1[r] = -1e30f;
            }
        }

        // ---- online softmax (all values in log2e units; exp2 native) ----
        float pm = fmaxf(vmax16(st0), vmax16(st1));
        u32x2 sm = plswap(__float_as_uint(pm), __float_as_uint(pm));
        pm = fmaxf(__uint_as_float(sm[0]), __uint_as_float(sm[1]));
        float mnew = fmaxf(m_run, pm);
        float sc = __builtin_exp2f(m_run - mnew);
        #pragma unroll
        for (int r = 0; r < 16; ++r) {
            st0[r] = __builtin_exp2f(st0[r] - mnew);
            st1[r] = __builtin_exp2f(st1[r] - mnew);
        }
        float ps = vsum16(st0) + vsum16(st1);
        u32x2 ss = plswap(__float_as_uint(ps), __float_as_uint(ps));
        ps = __uint_as_float(ss[0]) + __uint_as_float(ss[1]);
        l_run = l_run * sc + ps;
        m_run = mnew;
        #pragma unroll
        for (int r = 0; r < 16; ++r) { o0[r] *= sc; o1[r] *= sc; }

        // ---- P^T -> bf16 B-fragments in-register (cvt_pk pairs + permlane32_swap) ----
        bf16x8 bp[4];
        {
            uint32_t u0 = pk2bf(st0[0],  st0[1]),  u1 = pk2bf(st0[2],  st0[3]);
            uint32_t u2 = pk2bf(st0[4],  st0[5]),  u3 = pk2bf(st0[6],  st0[7]);
            uint32_t u4 = pk2bf(st0[8],  st0[9]),  u5 = pk2bf(st0[10], st0[11]);
            uint32_t u6 = pk2bf(st0[12], st0[13]), u7 = pk2bf(st0[14], st0[15]);
            u32x2 s02 = plswap(u0, u2), s13 = plswap(u1, u3);
            bp[0] = mk8(s02[0], s13[0], s02[1], s13[1]);
            u32x2 s46 = plswap(u4, u6), s57 = plswap(u5, u7);
            bp[1] = mk8(s46[0], s57[0], s46[1], s57[1]);
        }
        {
            uint32_t u0 = pk2bf(st1[0],  st1[1]),  u1 = pk2bf(st1[2],  st1[3]);
            uint32_t u2 = pk2bf(st1[4],  st1[5]),  u3 = pk2bf(st1[6],  st1[7]);
            uint32_t u4 = pk2bf(st1[8],  st1[9]),  u5 = pk2bf(st1[10], st1[11]);
            uint32_t u6 = pk2bf(st1[12], st1[13]), u7 = pk2bf(st1[14], st1[15]);
            u32x2 s02 = plswap(u0, u2), s13 = plswap(u1, u3);
            bp[2] = mk8(s02[0], s13[0], s02[1], s13[1]);
            u32x2 s46 = plswap(u4, u6), s57 = plswap(u5, u7);
            bp[3] = mk8(s46[0], s57[0], s46[1], s57[1]);
        }

        // ---- O^T += V^T * P^T ----
        #pragma unroll
        for (int x = 0; x < 4; ++x) {
            int cb = (x * 16 + h * 8) * 2;
            bf16x8 a0 = lds8(vlsb + swz(ln,      cb));
            bf16x8 a1 = lds8(vlsb + swz(ln + 32, cb));
            o0 = __builtin_amdgcn_mfma_f32_32x32x16_bf16(a0, bp[x], o0, 0, 0, 0);
            o1 = __builtin_amdgcn_mfma_f32_32x32x16_bf16(a1, bp[x], o1, 0, 0, 0);
        }
        __syncthreads();
    }

    // ---- epilogue: O = O^T / l, store transposed back to [q][d] ----
    float inv = 1.0f / l_run;
    float* op = O + bOff + (size_t)qrow * DIM;
    #pragma unroll
    for (int a = 0; a < 4; ++a) {
        float4 w0, w1;
        w0.x = o0[4*a+0] * inv; w0.y = o0[4*a+1] * inv;
        w0.z = o0[4*a+2] * inv; w0.w = o0[4*a+3] * inv;
        w1.x = o1[4*a+0] * inv; w1.y = o1[4*a+1] * inv;
        w1.z = o1[4*a+2] * inv; w1.w = o1[4*a+3] * inv;
        *(float4*)(op + 8*a + 4*h)      = w0;   // d = (r&3)+8*(r>>2)+4h, tile0
        *(float4*)(op + 32 + 8*a + 4*h) = w1;   // tile1: +32
    }
}

extern "C" void kernel_launch(void* const* d_in, const int* in_sizes, int n_in,
                              void* d_out, int out_size, void* d_ws, size_t ws_size,
                              hipStream_t stream) {
    const float* q  = (const float*)d_in[0];
    const float* k  = (const float*)d_in[1];
    const float* v  = (const float*)d_in[2];
    const int*   vl = (const int*)d_in[3];
    float* out = (float*)d_out;

    dim3 grid(BATCH * (SEQ / QBLK));   // 512 blocks: bid = qt*16 + b
    dim3 block(NTHR);
    hipLaunchKernelGGL(attn_fwd, grid, block, 0, stream, q, k, v, vl, out);
}

// Round 2
// 59.974 us; speedup vs baseline: 1.3676x; 1.3676x over previous
//
#include <hip/hip_runtime.h>
#include <hip/hip_bf16.h>
#include <stdint.h>

// Flash-attention forward: B=16, Lq=Lk=2048, D=64, fp32 in/out, bf16 MFMA.
// Round 2: 8-wave blocks, 4-way KV split per block (online-softmax partials
// combined through LDS), register-transposed V staging with b64 writes.

#define BATCH 16
#define SEQ   2048
#define DIM   64
#define KBLK  64
#define QBLK  64      // per block: 2 q-halves x 32 q-rows
#define NSPLIT 4
#define NTHR  512

typedef __bf16 bf16x8 __attribute__((ext_vector_type(8)));
typedef float  f32x16 __attribute__((ext_vector_type(16)));
typedef unsigned int u32x2 __attribute__((ext_vector_type(2)));

static constexpr float QSCALE = 0.125f * 1.44269504088896340736f; // 1/sqrt(D)*log2(e)

__device__ __forceinline__ uint32_t pk2bf(float a, float b) {
    union { __hip_bfloat162 h; uint32_t u; } c;
    c.h = __float22bfloat162_rn(make_float2(a, b));
    return c.u;
}
// XOR swizzle: row-major [row][64 bf16] tile, 128B rows; spreads the
// 32-lane column read across 8 16B slots (guide G4).
__device__ __forceinline__ uint32_t swz(uint32_t row, uint32_t colByte) {
    return row * 128u + (colByte ^ ((row & 7u) << 4));
}
__device__ __forceinline__ bf16x8 lds8(const char* p) {
    union { uint4 q; bf16x8 v; } c;
    c.q = *(const uint4*)p;
    return c.v;
}
__device__ __forceinline__ bf16x8 mk8(uint32_t w0, uint32_t w1, uint32_t w2, uint32_t w3) {
    union { uint32_t u[4]; bf16x8 v; } c;
    c.u[0] = w0; c.u[1] = w1; c.u[2] = w2; c.u[3] = w3;
    return c.v;
}
__device__ __forceinline__ u32x2 plswap(uint32_t a, uint32_t b) {
    return __builtin_amdgcn_permlane32_swap(a, b, false, false);
}
__device__ __forceinline__ float vmax16(const f32x16& v) {
    float a = fmaxf(fmaxf(v[0], v[1]), fmaxf(v[2], v[3]));
    float b = fmaxf(fmaxf(v[4], v[5]), fmaxf(v[6], v[7]));
    float c = fmaxf(fmaxf(v[8], v[9]), fmaxf(v[10], v[11]));
    float d = fmaxf(fmaxf(v[12], v[13]), fmaxf(v[14], v[15]));
    return fmaxf(fmaxf(a, b), fmaxf(c, d));
}
__device__ __forceinline__ float vsum16(const f32x16& v) {
    float a = (v[0] + v[1]) + (v[2] + v[3]);
    float b = (v[4] + v[5]) + (v[6] + v[7]);
    float c = (v[8] + v[9]) + (v[10] + v[11]);
    float d = (v[12] + v[13]) + (v[14] + v[15]);
    return (a + b) + (c + d);
}

__global__ __launch_bounds__(NTHR, 4) void attn_fwd(
        const float* __restrict__ Q, const float* __restrict__ K,
        const float* __restrict__ V, const int* __restrict__ VL,
        float* __restrict__ O)
{
    // [split][0]=K tile [k][d], [split][1]=V^T tile [d][k]; bf16, swizzled.
    __shared__ unsigned short lds[NSPLIT][2][KBLK * DIM];

    const int tid  = threadIdx.x;
    const int bid  = blockIdx.x;
    const int b    = bid & (BATCH - 1);   // consecutive bids -> different batch
    const int qt   = bid >> 4;            // 0..31
    const int qb   = qt * QBLK;
    const int w    = tid >> 6;            // wave 0..7
    const int qhalf = w & 1;
    const int split = w >> 1;             // 0..3
    const int lane = tid & 63;
    const int h    = lane >> 5;           // lane half
    const int ln   = lane & 31;
    const int ptid = tid & 127;           // tid within the 2-wave staging pair

    const int valid  = VL[b];
    const int ntiles = (valid + KBLK - 1) / KBLK;
    const int nit    = (ntiles + NSPLIT - 1) / NSPLIT;  // == split0's tile count

    const size_t bOff = (size_t)b * SEQ * DIM;
    const int qrow = qb + qhalf * 32 + ln;

    // ---- Q fragments (B-operand layout for S^T = K * Q^T), scaled ----
    bf16x8 qf[4];
    {
        const float* qp = Q + bOff + (size_t)qrow * DIM;
        #pragma unroll
        for (int s = 0; s < 4; ++s) {
            int c0 = s * 16 + h * 8;
            float4 x = *(const float4*)(qp + c0);
            float4 y = *(const float4*)(qp + c0 + 4);
            qf[s] = mk8(pk2bf(x.x * QSCALE, x.y * QSCALE),
                        pk2bf(x.z * QSCALE, x.w * QSCALE),
                        pk2bf(y.x * QSCALE, y.y * QSCALE),
                        pk2bf(y.z * QSCALE, y.w * QSCALE));
        }
    }

    f32x16 o0, o1;           // O^T accumulators: tile0 d=0..31, tile1 d=32..63; col q=ln
    #pragma unroll
    for (int r = 0; r < 16; ++r) { o0[r] = 0.0f; o1[r] = 0.0f; }
    float m_run = -1e30f, l_run = 0.0f;

    const float* Kb = K + bOff;
    const float* Vb = V + bOff;
    char* kls = (char*)lds[split][0];
    char* vls = (char*)lds[split][1];

    for (int it = 0; it < nit; ++it) {
        const int kt = it * NSPLIT + split;
        const bool act = kt < ntiles;
        const int kb = kt * KBLK;

        if (act) {
            // ---- stage K (row-major) ----
            #pragma unroll
            for (int p = 0; p < 8; ++p) {
                int idx = p * 128 + ptid;            // 0..1023
                int r = idx >> 4;                    // k row 0..63
                int c = (idx & 15) * 4;              // d col 0..60
                float4 kx = *(const float4*)(Kb + (size_t)(kb + r) * DIM + c);
                *(uint2*)(kls + swz(r, c * 2)) =
                    make_uint2(pk2bf(kx.x, kx.y), pk2bf(kx.z, kx.w));
            }
            // ---- stage V transposed via in-register 4x4 transpose, b64 writes ----
            #pragma unroll
            for (int p = 0; p < 2; ++p) {
                int idx = p * 128 + ptid;            // 0..255
                int cq = idx & 15;                   // d quad 0..15
                int rq = idx >> 4;                   // k quad 0..15
                const float* vp = Vb + (size_t)(kb + rq * 4) * DIM + cq * 4;
                float4 v0 = *(const float4*)(vp);
                float4 v1 = *(const float4*)(vp + DIM);
                float4 v2 = *(const float4*)(vp + 2 * DIM);
                float4 v3 = *(const float4*)(vp + 3 * DIM);
                float a0[4] = {v0.x, v0.y, v0.z, v0.w};
                float a1[4] = {v1.x, v1.y, v1.z, v1.w};
                float a2[4] = {v2.x, v2.y, v2.z, v2.w};
                float a3[4] = {v3.x, v3.y, v3.z, v3.w};
                #pragma unroll
                for (int i = 0; i < 4; ++i) {
                    int row = cq * 4 + i;            // d
                    *(uint2*)(vls + swz(row, rq * 8)) =
                        make_uint2(pk2bf(a0[i], a1[i]), pk2bf(a2[i], a3[i]));
                }
            }
        }
        __syncthreads();

        if (act) {
            // ---- S^T = K * Q^T ----
            f32x16 st0, st1;
            #pragma unroll
            for (int r = 0; r < 16; ++r) { st0[r] = 0.0f; st1[r] = 0.0f; }
            #pragma unroll
            for (int s = 0; s < 4; ++s) {
                int cb = (s * 16 + h * 8) * 2;
                bf16x8 ka0 = lds8(kls + swz(ln,      cb));
                bf16x8 ka1 = lds8(kls + swz(ln + 32, cb));
                st0 = __builtin_amdgcn_mfma_f32_32x32x16_bf16(ka0, qf[s], st0, 0, 0, 0);
                st1 = __builtin_amdgcn_mfma_f32_32x32x16_bf16(ka1, qf[s], st1, 0, 0, 0);
            }

            // ---- mask partial tail tile ----
            if (kb + KBLK > valid) {
                #pragma unroll
                for (int r = 0; r < 16; ++r) {
                    int krel = (r & 3) + 8 * (r >> 2) + 4 * h;
                    if (kb + krel      >= valid) st0[r] = -1e30f;
                    if (kb + 32 + krel >= valid) st1[r] = -1e30f;
                }
            }

            // ---- online softmax (log2e units, native exp2) ----
            float pm = fmaxf(vmax16(st0), vmax16(st1));
            u32x2 sm = plswap(__float_as_uint(pm), __float_as_uint(pm));
            pm = fmaxf(__uint_as_float(sm[0]), __uint_as_float(sm[1]));
            float mnew = fmaxf(m_run, pm);
            float sc = __builtin_exp2f(m_run - mnew);
            #pragma unroll
            for (int r = 0; r < 16; ++r) {
                st0[r] = __builtin_exp2f(st0[r] - mnew);
                st1[r] = __builtin_exp2f(st1[r] - mnew);
            }
            float ps = vsum16(st0) + vsum16(st1);
            u32x2 ss = plswap(__float_as_uint(ps), __float_as_uint(ps));
            ps = __uint_as_float(ss[0]) + __uint_as_float(ss[1]);
            l_run = l_run * sc + ps;
            m_run = mnew;
            #pragma unroll
            for (int r = 0; r < 16; ++r) { o0[r] *= sc; o1[r] *= sc; }

            // ---- P^T -> bf16 B-fragments (cvt_pk pairs + permlane32_swap) ----
            bf16x8 bp[4];
            {
                uint32_t u0 = pk2bf(st0[0],  st0[1]),  u1 = pk2bf(st0[2],  st0[3]);
                uint32_t u2 = pk2bf(st0[4],  st0[5]),  u3 = pk2bf(st0[6],  st0[7]);
                uint32_t u4 = pk2bf(st0[8],  st0[9]),  u5 = pk2bf(st0[10], st0[11]);
                uint32_t u6 = pk2bf(st0[12], st0[13]), u7 = pk2bf(st0[14], st0[15]);
                u32x2 s02 = plswap(u0, u2), s13 = plswap(u1, u3);
                bp[0] = mk8(s02[0], s13[0], s02[1], s13[1]);
                u32x2 s46 = plswap(u4, u6), s57 = plswap(u5, u7);
                bp[1] = mk8(s46[0], s57[0], s46[1], s57[1]);
            }
            {
                uint32_t u0 = pk2bf(st1[0],  st1[1]),  u1 = pk2bf(st1[2],  st1[3]);
                uint32_t u2 = pk2bf(st1[4],  st1[5]),  u3 = pk2bf(st1[6],  st1[7]);
                uint32_t u4 = pk2bf(st1[8],  st1[9]),  u5 = pk2bf(st1[10], st1[11]);
                uint32_t u6 = pk2bf(st1[12], st1[13]), u7 = pk2bf(st1[14], st1[15]);
                u32x2 s02 = plswap(u0, u2), s13 = plswap(u1, u3);
                bp[2] = mk8(s02[0], s13[0], s02[1], s13[1]);
                u32x2 s46 = plswap(u4, u6), s57 = plswap(u5, u7);
                bp[3] = mk8(s46[0], s57[0], s46[1], s57[1]);
            }

            // ---- O^T += V^T * P^T ----
            #pragma unroll
            for (int x = 0; x < 4; ++x) {
                int cb = (x * 16 + h * 8) * 2;
                bf16x8 va0 = lds8(vls + swz(ln,      cb));
                bf16x8 va1 = lds8(vls + swz(ln + 32, cb));
                o0 = __builtin_amdgcn_mfma_f32_32x32x16_bf16(va0, bp[x], o0, 0, 0, 0);
                o1 = __builtin_amdgcn_mfma_f32_32x32x16_bf16(va1, bp[x], o1, 0, 0, 0);
            }
        }
        __syncthreads();
    }

    // ---- cross-split combine through LDS (tiles are dead now) ----
    // Region per (qhalf, split 1..3): 32 regs x 64 lanes O^T + m + l.
    const int CSTRIDE = 32 * 64 + 128;  // floats
    float* comb = (float*)lds;
    if (split != 0) {
        float* base = comb + (size_t)(qhalf * 3 + (split - 1)) * CSTRIDE;
        #pragma unroll
        for (int r = 0; r < 16; ++r) {
            base[r * 64 + lane]        = o0[r];
            base[(r + 16) * 64 + lane] = o1[r];
        }
        base[2048 + lane]      = m_run;
        base[2048 + 64 + lane] = l_run;
    }
    __syncthreads();
    if (split == 0) {
        float M = m_run;
        #pragma unroll
        for (int j = 0; j < 3; ++j)
            M = fmaxf(M, comb[(size_t)(qhalf * 3 + j) * CSTRIDE + 2048 + lane]);
        float sc0 = __builtin_exp2f(m_run - M);
        float lt = l_run * sc0;
        #pragma unroll
        for (int r = 0; r < 16; ++r) { o0[r] *= sc0; o1[r] *= sc0; }
        #pragma unroll
        for (int j = 0; j < 3; ++j) {
            float* base = comb + (size_t)(qhalf * 3 + j) * CSTRIDE;
            float mj = base[2048 + lane];
            float lj = base[2048 + 64 + lane];
            float scj = __builtin_exp2f(mj - M);
            lt += lj * scj;
            #pragma unroll
            for (int r = 0; r < 16; ++r) {
                o0[r] += scj * base[r * 64 + lane];
                o1[r] += scj * base[(r + 16) * 64 + lane];
            }
        }
        // ---- epilogue: O = O^T / l, store back to [q][d] ----
        float inv = 1.0f / lt;
        float* op = O + bOff + (size_t)qrow * DIM;
        #pragma unroll
        for (int a = 0; a < 4; ++a) {
            float4 w0, w1;
            w0.x = o0[4*a+0] * inv; w0.y = o0[4*a+1] * inv;
            w0.z = o0[4*a+2] * inv; w0.w = o0[4*a+3] * inv;
            w1.x = o1[4*a+0] * inv; w1.y = o1[4*a+1] * inv;
            w1.z = o1[4*a+2] * inv; w1.w = o1[4*a+3] * inv;
            *(float4*)(op + 8*a + 4*h)      = w0;   // d = (r&3)+8*(r>>2)+4h, tile0
            *(float4*)(op + 32 + 8*a + 4*h) = w1;   // tile1: +32
        }
    }
}

extern "C" void kernel_launch(void* const* d_in, const int* in_sizes, int n_in,
                              void* d_out, int out_size, void* d_ws, size_t ws_size,
                              hipStream_t stream) {
    const float* q  = (const float*)d_in[0];
    const float* k  = (const float*)d_in[1];
    const float* v  = (const float*)d_in[2];
    const int*   vl = (const int*)d_in[3];
    float* out = (float*)d_out;

    dim3 grid(BATCH * (SEQ / QBLK));   // 512 blocks: bid = qt*16 + b
    dim3 block(NTHR);
    hipLaunchKernelGGL(attn_fwd, grid, block, 0, stream, q, k, v, vl, out);
}

// Round 3
// 54.680 us; speedup vs baseline: 1.5000x; 1.0968x over previous
//
#include <hip/hip_runtime.h>
#include <hip/hip_bf16.h>
#include <stdint.h>

// Flash-attention forward: B=16, Lq=Lk=2048, D=64, fp32 in/out, bf16 MFMA.
// Round 3: 4-wave 256-thread blocks (2 q-halves x 2 KV-splits), VGPR cap 256
// (round 2's launch_bounds(512,4) forced 128 -> scratch spills: WRITE_SIZE
// 17.4MB vs 8.2MB output). Verified swapped-MFMA + in-register softmax kept.

#define BATCH 16
#define SEQ   2048
#define DIM   64
#define KBLK  64
#define QBLK  64      // per block: 2 q-halves x 32 q-rows
#define NSPLIT 2
#define NTHR  256

typedef __bf16 bf16x8 __attribute__((ext_vector_type(8)));
typedef float  f32x16 __attribute__((ext_vector_type(16)));
typedef unsigned int u32x2 __attribute__((ext_vector_type(2)));

static constexpr float QSCALE = 0.125f * 1.44269504088896340736f; // 1/sqrt(D)*log2(e)

__device__ __forceinline__ uint32_t pk2bf(float a, float b) {
    union { __hip_bfloat162 h; uint32_t u; } c;
    c.h = __float22bfloat162_rn(make_float2(a, b));
    return c.u;
}
// XOR swizzle: row-major [row][64 bf16] tile, 128B rows; spreads the
// 32-lane column read across 8 16B slots (guide G4).
__device__ __forceinline__ uint32_t swz(uint32_t row, uint32_t colByte) {
    return row * 128u + (colByte ^ ((row & 7u) << 4));
}
__device__ __forceinline__ bf16x8 lds8(const char* p) {
    union { uint4 q; bf16x8 v; } c;
    c.q = *(const uint4*)p;
    return c.v;
}
__device__ __forceinline__ bf16x8 mk8(uint32_t w0, uint32_t w1, uint32_t w2, uint32_t w3) {
    union { uint32_t u[4]; bf16x8 v; } c;
    c.u[0] = w0; c.u[1] = w1; c.u[2] = w2; c.u[3] = w3;
    return c.v;
}
__device__ __forceinline__ u32x2 plswap(uint32_t a, uint32_t b) {
    return __builtin_amdgcn_permlane32_swap(a, b, false, false);
}
__device__ __forceinline__ float vmax16(const f32x16& v) {
    float a = fmaxf(fmaxf(v[0], v[1]), fmaxf(v[2], v[3]));
    float b = fmaxf(fmaxf(v[4], v[5]), fmaxf(v[6], v[7]));
    float c = fmaxf(fmaxf(v[8], v[9]), fmaxf(v[10], v[11]));
    float d = fmaxf(fmaxf(v[12], v[13]), fmaxf(v[14], v[15]));
    return fmaxf(fmaxf(a, b), fmaxf(c, d));
}
__device__ __forceinline__ float vsum16(const f32x16& v) {
    float a = (v[0] + v[1]) + (v[2] + v[3]);
    float b = (v[4] + v[5]) + (v[6] + v[7]);
    float c = (v[8] + v[9]) + (v[10] + v[11]);
    float d = (v[12] + v[13]) + (v[14] + v[15]);
    return (a + b) + (c + d);
}

__global__ __launch_bounds__(NTHR, 2) void attn_fwd(
        const float* __restrict__ Q, const float* __restrict__ K,
        const float* __restrict__ V, const int* __restrict__ VL,
        float* __restrict__ O)
{
    // [split][0]=K tile [k][d], [split][1]=V^T tile [d][k]; bf16, swizzled.
    __shared__ unsigned short lds[NSPLIT][2][KBLK * DIM];   // 32 KB

    const int tid  = threadIdx.x;
    const int bid  = blockIdx.x;
    const int b    = bid & (BATCH - 1);   // consecutive bids -> different batch
    const int qt   = bid >> 4;            // 0..31
    const int qb   = qt * QBLK;
    const int qhalf = (tid >> 6) & 1;
    const int split = tid >> 7;           // 0..1
    const int lane = tid & 63;
    const int h    = lane >> 5;           // lane half
    const int ln   = lane & 31;
    const int ptid = tid & 127;           // tid within the 2-wave staging pair

    const int valid  = VL[b];
    const int ntiles = (valid + KBLK - 1) / KBLK;
    const int nit    = (ntiles + NSPLIT - 1) / NSPLIT;  // == split0's tile count

    const size_t bOff = (size_t)b * SEQ * DIM;
    const int qrow = qb + qhalf * 32 + ln;

    // ---- Q fragments (B-operand layout for S^T = K * Q^T), scaled ----
    bf16x8 qf[4];
    {
        const float* qp = Q + bOff + (size_t)qrow * DIM;
        #pragma unroll
        for (int s = 0; s < 4; ++s) {
            int c0 = s * 16 + h * 8;
            float4 x = *(const float4*)(qp + c0);
            float4 y = *(const float4*)(qp + c0 + 4);
            qf[s] = mk8(pk2bf(x.x * QSCALE, x.y * QSCALE),
                        pk2bf(x.z * QSCALE, x.w * QSCALE),
                        pk2bf(y.x * QSCALE, y.y * QSCALE),
                        pk2bf(y.z * QSCALE, y.w * QSCALE));
        }
    }

    f32x16 o0, o1;           // O^T accumulators: tile0 d=0..31, tile1 d=32..63; col q=ln
    #pragma unroll
    for (int r = 0; r < 16; ++r) { o0[r] = 0.0f; o1[r] = 0.0f; }
    float m_run = -1e30f, l_run = 0.0f;

    const float* Kb = K + bOff;
    const float* Vb = V + bOff;
    char* kls = (char*)lds[split][0];
    char* vls = (char*)lds[split][1];

    for (int it = 0; it < nit; ++it) {
        const int kt = it * NSPLIT + split;
        const bool act = kt < ntiles;
        const int kb = kt * KBLK;

        if (act) {
            // ---- stage K (row-major) ----
            #pragma unroll
            for (int p = 0; p < 8; ++p) {
                int idx = p * 128 + ptid;            // 0..1023
                int r = idx >> 4;                    // k row 0..63
                int c = (idx & 15) * 4;              // d col 0..60
                float4 kx = *(const float4*)(Kb + (size_t)(kb + r) * DIM + c);
                *(uint2*)(kls + swz(r, c * 2)) =
                    make_uint2(pk2bf(kx.x, kx.y), pk2bf(kx.z, kx.w));
            }
            // ---- stage V transposed via in-register 4x4 transpose, b64 writes ----
            #pragma unroll
            for (int p = 0; p < 2; ++p) {
                int idx = p * 128 + ptid;            // 0..255
                int cq = idx & 15;                   // d quad 0..15
                int rq = idx >> 4;                   // k quad 0..15
                const float* vp = Vb + (size_t)(kb + rq * 4) * DIM + cq * 4;
                float4 v0 = *(const float4*)(vp);
                float4 v1 = *(const float4*)(vp + DIM);
                float4 v2 = *(const float4*)(vp + 2 * DIM);
                float4 v3 = *(const float4*)(vp + 3 * DIM);
                float a0[4] = {v0.x, v0.y, v0.z, v0.w};
                float a1[4] = {v1.x, v1.y, v1.z, v1.w};
                float a2[4] = {v2.x, v2.y, v2.z, v2.w};
                float a3[4] = {v3.x, v3.y, v3.z, v3.w};
                #pragma unroll
                for (int i = 0; i < 4; ++i) {
                    int row = cq * 4 + i;            // d
                    *(uint2*)(vls + swz(row, rq * 8)) =
                        make_uint2(pk2bf(a0[i], a1[i]), pk2bf(a2[i], a3[i]));
                }
            }
        }
        __syncthreads();

        if (act) {
            // ---- S^T = K * Q^T ----
            f32x16 st0, st1;
            #pragma unroll
            for (int r = 0; r < 16; ++r) { st0[r] = 0.0f; st1[r] = 0.0f; }
            #pragma unroll
            for (int s = 0; s < 4; ++s) {
                int cb = (s * 16 + h * 8) * 2;
                bf16x8 ka0 = lds8(kls + swz(ln,      cb));
                bf16x8 ka1 = lds8(kls + swz(ln + 32, cb));
                st0 = __builtin_amdgcn_mfma_f32_32x32x16_bf16(ka0, qf[s], st0, 0, 0, 0);
                st1 = __builtin_amdgcn_mfma_f32_32x32x16_bf16(ka1, qf[s], st1, 0, 0, 0);
            }

            // ---- mask partial tail tile (reproduces -1e6 fill: weight 0) ----
            if (kb + KBLK > valid) {
                #pragma unroll
                for (int r = 0; r < 16; ++r) {
                    int krel = (r & 3) + 8 * (r >> 2) + 4 * h;
                    if (kb + krel      >= valid) st0[r] = -1e30f;
                    if (kb + 32 + krel >= valid) st1[r] = -1e30f;
                }
            }

            // ---- online softmax (log2e units, native exp2) ----
            float pm = fmaxf(vmax16(st0), vmax16(st1));
            u32x2 sm = plswap(__float_as_uint(pm), __float_as_uint(pm));
            pm = fmaxf(__uint_as_float(sm[0]), __uint_as_float(sm[1]));
            float mnew = fmaxf(m_run, pm);
            float sc = __builtin_exp2f(m_run - mnew);
            #pragma unroll
            for (int r = 0; r < 16; ++r) {
                st0[r] = __builtin_exp2f(st0[r] - mnew);
                st1[r] = __builtin_exp2f(st1[r] - mnew);
            }
            float ps = vsum16(st0) + vsum16(st1);
            u32x2 ss = plswap(__float_as_uint(ps), __float_as_uint(ps));
            ps = __uint_as_float(ss[0]) + __uint_as_float(ss[1]);
            l_run = l_run * sc + ps;
            m_run = mnew;
            #pragma unroll
            for (int r = 0; r < 16; ++r) { o0[r] *= sc; o1[r] *= sc; }

            // ---- P^T -> bf16 B-fragments (cvt_pk pairs + permlane32_swap) ----
            bf16x8 bp[4];
            {
                uint32_t u0 = pk2bf(st0[0],  st0[1]),  u1 = pk2bf(st0[2],  st0[3]);
                uint32_t u2 = pk2bf(st0[4],  st0[5]),  u3 = pk2bf(st0[6],  st0[7]);
                uint32_t u4 = pk2bf(st0[8],  st0[9]),  u5 = pk2bf(st0[10], st0[11]);
                uint32_t u6 = pk2bf(st0[12], st0[13]), u7 = pk2bf(st0[14], st0[15]);
                u32x2 s02 = plswap(u0, u2), s13 = plswap(u1, u3);
                bp[0] = mk8(s02[0], s13[0], s02[1], s13[1]);
                u32x2 s46 = plswap(u4, u6), s57 = plswap(u5, u7);
                bp[1] = mk8(s46[0], s57[0], s46[1], s57[1]);
            }
            {
                uint32_t u0 = pk2bf(st1[0],  st1[1]),  u1 = pk2bf(st1[2],  st1[3]);
                uint32_t u2 = pk2bf(st1[4],  st1[5]),  u3 = pk2bf(st1[6],  st1[7]);
                uint32_t u4 = pk2bf(st1[8],  st1[9]),  u5 = pk2bf(st1[10], st1[11]);
                uint32_t u6 = pk2bf(st1[12], st1[13]), u7 = pk2bf(st1[14], st1[15]);
                u32x2 s02 = plswap(u0, u2), s13 = plswap(u1, u3);
                bp[2] = mk8(s02[0], s13[0], s02[1], s13[1]);
                u32x2 s46 = plswap(u4, u6), s57 = plswap(u5, u7);
                bp[3] = mk8(s46[0], s57[0], s46[1], s57[1]);
            }

            // ---- O^T += V^T * P^T ----
            #pragma unroll
            for (int x = 0; x < 4; ++x) {
                int cb = (x * 16 + h * 8) * 2;
                bf16x8 va0 = lds8(vls + swz(ln,      cb));
                bf16x8 va1 = lds8(vls + swz(ln + 32, cb));
                o0 = __builtin_amdgcn_mfma_f32_32x32x16_bf16(va0, bp[x], o0, 0, 0, 0);
                o1 = __builtin_amdgcn_mfma_f32_32x32x16_bf16(va1, bp[x], o1, 0, 0, 0);
            }
        }
        __syncthreads();
    }

    // ---- cross-split combine through LDS (tiles are dead now) ----
    // Region per qhalf (written by split 1): 32 regs x 64 lanes O^T + m + l.
    const int CSTRIDE = 32 * 64 + 128;  // floats
    float* comb = (float*)lds;
    if (split != 0) {
        float* base = comb + (size_t)qhalf * CSTRIDE;
        #pragma unroll
        for (int r = 0; r < 16; ++r) {
            base[r * 64 + lane]        = o0[r];
            base[(r + 16) * 64 + lane] = o1[r];
        }
        base[2048 + lane]      = m_run;
        base[2048 + 64 + lane] = l_run;
    }
    __syncthreads();
    if (split == 0) {
        float* base = comb + (size_t)qhalf * CSTRIDE;
        float mj = base[2048 + lane];
        float lj = base[2048 + 64 + lane];
        float M  = fmaxf(m_run, mj);
        float sc0 = __builtin_exp2f(m_run - M);
        float scj = __builtin_exp2f(mj - M);
        float lt = l_run * sc0 + lj * scj;
        float inv = 1.0f / lt;
        float* op = O + bOff + (size_t)qrow * DIM;
        #pragma unroll
        for (int a = 0; a < 4; ++a) {
            float4 w0, w1;
            w0.x = (o0[4*a+0]*sc0 + scj*base[(4*a+0)*64 + lane]) * inv;
            w0.y = (o0[4*a+1]*sc0 + scj*base[(4*a+1)*64 + lane]) * inv;
            w0.z = (o0[4*a+2]*sc0 + scj*base[(4*a+2)*64 + lane]) * inv;
            w0.w = (o0[4*a+3]*sc0 + scj*base[(4*a+3)*64 + lane]) * inv;
            w1.x = (o1[4*a+0]*sc0 + scj*base[(4*a+16)*64 + lane]) * inv;
            w1.y = (o1[4*a+1]*sc0 + scj*base[(4*a+17)*64 + lane]) * inv;
            w1.z = (o1[4*a+2]*sc0 + scj*base[(4*a+18)*64 + lane]) * inv;
            w1.w = (o1[4*a+3]*sc0 + scj*base[(4*a+19)*64 + lane]) * inv;
            *(float4*)(op + 8*a + 4*h)      = w0;   // d = (r&3)+8*(r>>2)+4h, tile0
            *(float4*)(op + 32 + 8*a + 4*h) = w1;   // tile1: +32
        }
    }
}

extern "C" void kernel_launch(void* const* d_in, const int* in_sizes, int n_in,
                              void* d_out, int out_size, void* d_ws, size_t ws_size,
                              hipStream_t stream) {
    const float* q  = (const float*)d_in[0];
    const float* k  = (const float*)d_in[1];
    const float* v  = (const float*)d_in[2];
    const int*   vl = (const int*)d_in[3];
    float* out = (float*)d_out;

    dim3 grid(BATCH * (SEQ / QBLK));   // 512 blocks: bid = qt*16 + b
    dim3 block(NTHR);
    hipLaunchKernelGGL(attn_fwd, grid, block, 0, stream, q, k, v, vl, out);
}